// Round 1
// baseline (848.823 us; speedup 1.0000x reference)
//
#include <hip/hip_runtime.h>
#include <math.h>

#define D      256
#define K      16384
#define NPTS   8192
#define KSPLIT 16
#define KRANGE (K / KSPLIT)   // 1024 ks per block
#define BN     64
#define BK     256
#define DK     16
#define BKP    260            // padded LDS stride for ew tile (k-major rows)

// Output layout in d_out (all float32):
//   [0)              zq_out   [8,256,32,32]  2097152
//   [2097152)        indices  [8192]         8192
//   [2105344)        bit_idx  [8,32,32,256]  2097152
//   [4202496)        loss     [1]            1
#define O_IDX  2097152
#define O_BIT  2105344
#define O_LOSS 4202496

// ---------------- Kernel A: L2-normalize codebook rows ----------------
__global__ __launch_bounds__(256) void normalize_rows(const float* __restrict__ E,
                                                      float* __restrict__ ew) {
    const int row = blockIdx.x;
    const int tid = threadIdx.x;
    float x = E[(size_t)row * D + tid];
    float s = x * x;
    #pragma unroll
    for (int o = 32; o > 0; o >>= 1) s += __shfl_xor(s, o);
    __shared__ float ws_[4];
    if ((tid & 63) == 0) ws_[tid >> 6] = s;
    __syncthreads();
    float tot = ws_[0] + ws_[1] + ws_[2] + ws_[3];
    float den = fmaxf(sqrtf(tot), 1e-12f);
    ew[(size_t)row * D + tid] = x / den;
}

// ------------- Kernel B: fused fp32 GEMM + running argmax -------------
// grid = (NPTS/BN, KSPLIT), block = 256
// thread tile: 8 points x 8 ks; tp = tid>>5 (0..7), tk = tid&31 (0..31)
// thread's ks within a 256-wide k tile: {tk*4+j} and {128+tk*4+j}
__global__ __launch_bounds__(256) void score_argmax(const float* __restrict__ z,
                                                    const float* __restrict__ ew,
                                                    float* __restrict__ pv,
                                                    int* __restrict__ pidx) {
    __shared__ float zs[DK * BN];        // 4 KB   [d][point]
    __shared__ float es[DK * BKP];       // 16.25KB[d][k] (padded)
    __shared__ float red_v[256 * 8];     // 8 KB
    __shared__ int   red_i[256 * 8];     // 8 KB

    const int tid  = threadIdx.x;
    const int tk   = tid & 31;
    const int tp   = tid >> 5;
    const int n0   = blockIdx.x * BN;
    const int b    = n0 >> 10;
    const int off0 = n0 & 1023;
    const int kbase = blockIdx.y * KRANGE;
    const float* zg = z + (size_t)b * D * 1024 + off0;

    float bestv[8];
    int   besti[8];
    #pragma unroll
    for (int i = 0; i < 8; ++i) { bestv[i] = -INFINITY; besti[i] = 0; }

    for (int kt = 0; kt < KRANGE; kt += BK) {
        float acc[8][8];
        #pragma unroll
        for (int i = 0; i < 8; ++i)
            #pragma unroll
            for (int j = 0; j < 8; ++j) acc[i][j] = 0.f;

        for (int dc = 0; dc < D; dc += DK) {
            __syncthreads();
            // stage z chunk: 16 d-rows x 64 contiguous points
            {
                const int c  = tid >> 4;   // 0..15 d-row
                const int pg = tid & 15;   // point group (x4)
                float4 v = *(const float4*)(zg + (size_t)(dc + c) * 1024 + pg * 4);
                *(float4*)&zs[c * BN + pg * 4] = v;
            }
            // stage ew chunk: 256 k-rows x 16 d, transpose into es[d][k]
            {
                const int cg = (tid & 3) * 4;  // d sub-col
                const int rr = tid >> 2;       // 0..63
                #pragma unroll
                for (int it = 0; it < 4; ++it) {
                    const int r = it * 64 + rr;
                    float4 v = *(const float4*)(ew + (size_t)(kbase + kt + r) * D + dc + cg);
                    es[(cg + 0) * BKP + r] = v.x;
                    es[(cg + 1) * BKP + r] = v.y;
                    es[(cg + 2) * BKP + r] = v.z;
                    es[(cg + 3) * BKP + r] = v.w;
                }
            }
            __syncthreads();
            #pragma unroll
            for (int dd = 0; dd < DK; ++dd) {
                float4 a0 = *(const float4*)&zs[dd * BN + tp * 8];
                float4 a1 = *(const float4*)&zs[dd * BN + tp * 8 + 4];
                float4 b0 = *(const float4*)&es[dd * BKP + tk * 4];
                float4 b1 = *(const float4*)&es[dd * BKP + 128 + tk * 4];
                const float a[8]  = {a0.x, a0.y, a0.z, a0.w, a1.x, a1.y, a1.z, a1.w};
                const float bb[8] = {b0.x, b0.y, b0.z, b0.w, b1.x, b1.y, b1.z, b1.w};
                #pragma unroll
                for (int i = 0; i < 8; ++i)
                    #pragma unroll
                    for (int j = 0; j < 8; ++j)
                        acc[i][j] = fmaf(a[i], bb[j], acc[i][j]);
            }
        }
        // running-argmax update (ascending k within thread -> strict > keeps first)
        const int kgA = kbase + kt + tk * 4;
        #pragma unroll
        for (int i = 0; i < 8; ++i) {
            #pragma unroll
            for (int j = 0; j < 8; ++j) {
                const int kk = (j < 4) ? (kgA + j) : (kgA + 128 + (j - 4));
                const float v = acc[i][j];
                if (v > bestv[i]) { bestv[i] = v; besti[i] = kk; }
            }
        }
    }

    #pragma unroll
    for (int i = 0; i < 8; ++i) {
        red_v[tid * 8 + i] = bestv[i];
        red_i[tid * 8 + i] = besti[i];
    }
    __syncthreads();
    if (tid < BN) {
        const int g = tid >> 3, pi_ = tid & 7;
        float bv = -INFINITY; int bi = 0x7fffffff;
        for (int m = 0; m < 32; ++m) {
            const int t = g * 32 + m;
            const float v = red_v[t * 8 + pi_];
            const int  ii = red_i[t * 8 + pi_];
            if (v > bv || (v == bv && ii < bi)) { bv = v; bi = ii; }
        }
        pv  [(size_t)(n0 + tid) * KSPLIT + blockIdx.y] = bv;
        pidx[(size_t)(n0 + tid) * KSPLIT + blockIdx.y] = bi;
    }
}

// ------------- Kernel C: split-reduce + gather + outputs -------------
__global__ __launch_bounds__(256) void finalize(const float* __restrict__ ew,
                                                const float* __restrict__ pv,
                                                const int* __restrict__ pidx,
                                                float* __restrict__ out) {
    const int n   = blockIdx.x;
    const int tid = threadIdx.x;
    __shared__ int sIdx;
    if (tid == 0) {
        float bv = -INFINITY; int bi = 0x7fffffff;
        #pragma unroll
        for (int s = 0; s < KSPLIT; ++s) {
            const float v = pv[(size_t)n * KSPLIT + s];
            const int  ii = pidx[(size_t)n * KSPLIT + s];
            if (v > bv || (v == bv && ii < bi)) { bv = v; bi = ii; }
        }
        sIdx = bi;
    }
    __syncthreads();
    const int idx = sIdx;
    const float v = ew[(size_t)idx * D + tid];
    const int b = n >> 10, off = n & 1023;
    // zq_out: [b, c, h, w]
    out[(size_t)(b * D + tid) * 1024 + off] = v;
    // bit_indices: [b, h, w, c], trunc-toward-zero like .astype(int32)
    const float S = 5.65685424949238019520675489683895f;  // sqrt(32) rounded to f32
    out[O_BIT + (size_t)n * D + tid] = (float)((int)(v * S) + 4);
    if (tid == 0) out[O_IDX + n] = (float)idx;
    if (n == 0 && tid == 0) out[O_LOSS] = 0.0f;
}

extern "C" void kernel_launch(void* const* d_in, const int* in_sizes, int n_in,
                              void* d_out, int out_size, void* d_ws, size_t ws_size,
                              hipStream_t stream) {
    const float* z = (const float*)d_in[0];
    const float* E = (const float*)d_in[1];
    float* out = (float*)d_out;

    float* ew   = (float*)d_ws;                         // 16384*256 f32 = 16 MB
    float* pv   = ew + (size_t)K * D;                   // 8192*16 f32
    int*   pidx = (int*)(pv + (size_t)NPTS * KSPLIT);   // 8192*16 i32

    normalize_rows<<<K, 256, 0, stream>>>(E, ew);
    dim3 gridB(NPTS / BN, KSPLIT);
    score_argmax<<<gridB, 256, 0, stream>>>(z, ew, pv, pidx);
    finalize<<<NPTS, 256, 0, stream>>>(ew, pv, pidx, out);
}

// Round 2
// 481.855 us; speedup vs baseline: 1.7616x; 1.7616x over previous
//
#include <hip/hip_runtime.h>
#include <math.h>

#define D      256
#define K      16384
#define NPTS   8192
#define DELTA  0.2f
#define LSTR   56   // LDS row stride in shorts (112B = 16B-aligned, uniform banks)

// d_out layout (all f32): zq[8,256,32,32] | indices[8192] | bit[8,32,32,256] | loss[1]
#define O_IDX  2097152
#define O_BIT  2105344
#define O_LOSS 4202496

typedef __attribute__((ext_vector_type(8))) short bf16x8;
typedef __attribute__((ext_vector_type(4))) float f32x4;

__device__ __forceinline__ unsigned f2s(float f) {
    unsigned u = __float_as_uint(f);
    return (u & 0x80000000u) ? ~u : (u | 0x80000000u);
}
__device__ __forceinline__ float s2f(unsigned s) {
    return __uint_as_float((s & 0x80000000u) ? (s & 0x7fffffffu) : ~s);
}
__device__ __forceinline__ unsigned short f2bf(float f) {  // round-to-nearest-even
    unsigned u = __float_as_uint(f);
    u += 0x7fffu + ((u >> 16) & 1u);
    return (unsigned short)(u >> 16);
}

__global__ void init_state(unsigned* __restrict__ gmax, unsigned long long* __restrict__ keys) {
    const int i = blockIdx.x * 256 + threadIdx.x;
    gmax[i] = 0u;
    keys[i] = 0ull;
}

// ---- normalize codebook rows; emit fp32 + bf16 copies ----
__global__ __launch_bounds__(256) void normalize_rows(const float* __restrict__ E,
                                                      float* __restrict__ ew32,
                                                      unsigned short* __restrict__ ewb) {
    const int row = blockIdx.x;
    const int tid = threadIdx.x;
    const float x = E[(size_t)row * D + tid];
    float s = x * x;
    #pragma unroll
    for (int o = 32; o > 0; o >>= 1) s += __shfl_xor(s, o);
    __shared__ float ws_[4];
    if ((tid & 63) == 0) ws_[tid >> 6] = s;
    __syncthreads();
    const float tot = ws_[0] + ws_[1] + ws_[2] + ws_[3];
    const float v = x / fmaxf(sqrtf(tot), 1e-12f);
    ew32[(size_t)row * D + tid] = v;
    ewb [(size_t)row * D + tid] = f2bf(v);
}

// ---- z [8,256,1024] -> zf [8192,256]; emit fp32 + bf16 copies ----
__global__ __launch_bounds__(256) void transpose_z(const float* __restrict__ z,
                                                   float* __restrict__ zf32,
                                                   unsigned short* __restrict__ zfb) {
    const int bi = blockIdx.x, tid = threadIdx.x;
    const int b = bi >> 4, hw0 = (bi & 15) * 64;
    __shared__ float t[64][65];
    for (int dc = 0; dc < D; dc += 64) {
        #pragma unroll
        for (int it = 0; it < 16; ++it) {
            const int idx = it * 256 + tid;
            const int dl = idx >> 6, hw = idx & 63;
            t[dl][hw] = z[(size_t)(b * 256 + dc + dl) * 1024 + hw0 + hw];
        }
        __syncthreads();
        #pragma unroll
        for (int it = 0; it < 16; ++it) {
            const int idx = it * 256 + tid;
            const int pl = idx >> 6, dl = idx & 63;
            const float v = t[dl][pl];
            const size_t o = (size_t)(b * 1024 + hw0 + pl) * D + dc + dl;
            zf32[o] = v;
            zfb[o]  = f2bf(v);
        }
        __syncthreads();
    }
}

// exact fp32 rescore: deterministic summation order, single emitted copy
__device__ __attribute__((noinline)) void rescore(const float* __restrict__ zf32,
                                                  const float* __restrict__ ew32,
                                                  int gp, int gc,
                                                  unsigned long long* __restrict__ keys) {
    const float4* ap = (const float4*)(zf32 + (size_t)gp * D);
    const float4* bp = (const float4*)(ew32 + (size_t)gc * D);
    float s = 0.f;
    #pragma unroll 4
    for (int i = 0; i < 64; ++i) {
        const float4 a = ap[i], b = bp[i];
        s = fmaf(a.x, b.x, fmaf(a.y, b.y, fmaf(a.z, b.z, fmaf(a.w, b.w, s))));
    }
    const unsigned long long key =
        ((unsigned long long)f2s(s) << 32) | (unsigned)(16383 - gc);
    atomicMax(keys + gp, key);
}

// ---- bf16 MFMA scores + per-point max + candidate rescore ----
// grid = (k_blocks, m_blocks=64), block tile 128 points x 128 codes
__global__ __launch_bounds__(256) void score_mfma(const unsigned short* __restrict__ zfb,
                                                  const unsigned short* __restrict__ ewb,
                                                  const float* __restrict__ zf32,
                                                  const float* __restrict__ ew32,
                                                  unsigned* __restrict__ gmax,
                                                  unsigned long long* __restrict__ keys,
                                                  int do_rescore) {
    __shared__ unsigned short za[128 * LSTR];
    __shared__ unsigned short eb[128 * LSTR];
    __shared__ unsigned smaxu[128];
    __shared__ float thr[128];

    const int tid  = threadIdx.x;
    const int lane = tid & 63, wave = tid >> 6;
    const int quad = lane >> 4, col = lane & 15;
    const int wm   = wave >> 1, wn = wave & 1;
    const int n0   = blockIdx.x * 128;
    const int m0   = blockIdx.y * 128;

    if (tid < 128) smaxu[tid] = 0u;

    f32x4 acc[4][4];
    #pragma unroll
    for (int i = 0; i < 4; ++i)
        #pragma unroll
        for (int j = 0; j < 4; ++j)
            acc[i][j] = (f32x4){0.f, 0.f, 0.f, 0.f};

    const int r0 = tid >> 2, s0 = tid & 3;

    for (int dc = 0; dc < D; dc += 32) {
        __syncthreads();
        #pragma unroll
        for (int p = 0; p < 2; ++p) {
            const int row = p * 64 + r0;
            const int4 va = *(const int4*)(zfb + (size_t)(m0 + row) * D + dc + s0 * 8);
            const int4 vb = *(const int4*)(ewb + (size_t)(n0 + row) * D + dc + s0 * 8);
            *(int4*)&za[row * LSTR + s0 * 8] = va;
            *(int4*)&eb[row * LSTR + s0 * 8] = vb;
        }
        __syncthreads();
        bf16x8 af[4], bfr[4];
        #pragma unroll
        for (int mt = 0; mt < 4; ++mt)
            af[mt] = *(const bf16x8*)&za[(wm * 64 + mt * 16 + col) * LSTR + quad * 8];
        #pragma unroll
        for (int nt = 0; nt < 4; ++nt)
            bfr[nt] = *(const bf16x8*)&eb[(wn * 64 + nt * 16 + col) * LSTR + quad * 8];
        #pragma unroll
        for (int mt = 0; mt < 4; ++mt)
            #pragma unroll
            for (int nt = 0; nt < 4; ++nt)
                acc[mt][nt] = __builtin_amdgcn_mfma_f32_16x16x32_bf16(af[mt], bfr[nt],
                                                                      acc[mt][nt], 0, 0, 0);
    }

    // per-point local max over this block's 128-code slice
    float pm[4][4];
    #pragma unroll
    for (int mt = 0; mt < 4; ++mt)
        #pragma unroll
        for (int r = 0; r < 4; ++r)
            pm[mt][r] = fmaxf(fmaxf(acc[mt][0][r], acc[mt][1][r]),
                              fmaxf(acc[mt][2][r], acc[mt][3][r]));
    #pragma unroll
    for (int off = 1; off < 16; off <<= 1)
        #pragma unroll
        for (int mt = 0; mt < 4; ++mt)
            #pragma unroll
            for (int r = 0; r < 4; ++r)
                pm[mt][r] = fmaxf(pm[mt][r], __shfl_xor(pm[mt][r], off));
    if (col == 0) {
        #pragma unroll
        for (int mt = 0; mt < 4; ++mt)
            #pragma unroll
            for (int r = 0; r < 4; ++r)
                atomicMax(&smaxu[wm * 64 + mt * 16 + quad * 4 + r], f2s(pm[mt][r]));
    }
    __syncthreads();
    if (tid < 128) {
        const unsigned mine = smaxu[tid];
        const unsigned old  = atomicMax(&gmax[m0 + tid], mine);
        if (do_rescore) thr[tid] = s2f(old > mine ? old : mine) - DELTA;
    }
    if (!do_rescore) return;
    __syncthreads();

    #pragma unroll
    for (int mt = 0; mt < 4; ++mt) {
        #pragma unroll
        for (int r = 0; r < 4; ++r) {
            const int p   = wm * 64 + mt * 16 + quad * 4 + r;
            const float tp = thr[p];
            #pragma unroll
            for (int nt = 0; nt < 4; ++nt) {
                if (acc[mt][nt][r] >= tp)
                    rescore(zf32, ew32, m0 + p, n0 + wn * 64 + nt * 16 + col, keys);
            }
        }
    }
}

// ---- gather + outputs ----
__global__ __launch_bounds__(256) void finalize(const float* __restrict__ ew32,
                                                const unsigned long long* __restrict__ keys,
                                                float* __restrict__ out) {
    const int n = blockIdx.x, tid = threadIdx.x;
    const unsigned long long key = keys[n];
    const int idx = 16383 - (int)(unsigned)(key & 0xffffffffull);
    const float v = ew32[(size_t)idx * D + tid];
    const int b = n >> 10, off = n & 1023;
    out[(size_t)(b * D + tid) * 1024 + off] = v;
    const float S = 5.65685424949238019520675489683895f;  // sqrt(32)
    out[O_BIT + (size_t)n * D + tid] = (float)((int)(v * S) + 4);
    if (tid == 0) out[O_IDX + n] = (float)idx;
    if (n == 0 && tid == 0) out[O_LOSS] = 0.0f;
}

extern "C" void kernel_launch(void* const* d_in, const int* in_sizes, int n_in,
                              void* d_out, int out_size, void* d_ws, size_t ws_size,
                              hipStream_t stream) {
    const float* z = (const float*)d_in[0];
    const float* E = (const float*)d_in[1];
    float* out = (float*)d_out;

    float* ew32          = (float*)d_ws;                                   // 16 MB
    float* zf32          = ew32 + (size_t)K * D;                           //  8 MB
    unsigned short* ewb  = (unsigned short*)(zf32 + (size_t)NPTS * D);     //  8 MB
    unsigned short* zfb  = ewb + (size_t)K * D;                            //  4 MB
    unsigned long long* keys = (unsigned long long*)(zfb + (size_t)NPTS * D); // 64 KB
    unsigned* gmax       = (unsigned*)(keys + NPTS);                       // 32 KB

    init_state<<<NPTS / 256, 256, 0, stream>>>(gmax, keys);
    normalize_rows<<<K, 256, 0, stream>>>(E, ew32, ewb);
    transpose_z<<<128, 256, 0, stream>>>(z, zf32, zfb);

    // pre-pass: codes [0, 4096) seed per-point global max (no rescore)
    dim3 gpre(32, NPTS / 128);
    score_mfma<<<gpre, 256, 0, stream>>>(zfb, ewb, zf32, ew32, gmax, keys, 0);
    // main pass: all codes, informed threshold, exact rescore of candidates
    dim3 gmain(K / 128, NPTS / 128);
    score_mfma<<<gmain, 256, 0, stream>>>(zfb, ewb, zf32, ew32, gmax, keys, 1);

    finalize<<<NPTS, 256, 0, stream>>>(ew32, keys, out);
}